// Round 4
// baseline (234.732 us; speedup 1.0000x reference)
//
#include <hip/hip_runtime.h>

typedef __bf16 bf16;
typedef __bf16 bf16x8 __attribute__((ext_vector_type(8)));
typedef __bf16 bf16x4 __attribute__((ext_vector_type(4)));
typedef float f32x4 __attribute__((ext_vector_type(4)));

#if __has_builtin(__builtin_amdgcn_exp2f)
#define EXP2(x) __builtin_amdgcn_exp2f(x)
#else
#define EXP2(x) exp2f(x)
#endif

__device__ __forceinline__ void gload_lds16(const void* g, void* l) {
  __builtin_amdgcn_global_load_lds(
      (const __attribute__((address_space(1))) void*)g,
      (__attribute__((address_space(3))) void*)l, 16, 0, 0);
}

__global__ __launch_bounds__(256) void cast_f32_bf16(const float* __restrict__ in,
                                                     bf16* __restrict__ out, int n) {
  int i = (blockIdx.x * 256 + threadIdx.x) * 4;
  if (i < n) {
    float4 v = *(const float4*)(in + i);
    bf16x4 o = {(bf16)v.x, (bf16)v.y, (bf16)v.z, (bf16)v.w};
    *(bf16x4*)(out + i) = o;
  }
}

// ---------------------------------------------------------------------------
// GEMM1: 256x256 tile, BK=64, 8 waves (2Mx4N), 8-phase counted-vmcnt schedule.
// A[2048][2048], B[6144][2048] bf16 row-major; C = A*B^T with qkv-split epi.
// LDS (dynamic 128KB): A[2 buf][8 kc][256 row]x16B, B same at +64KB.
// No pointer arrays into LDS (addrspacecast static-init bug) — offsets only.
// ---------------------------------------------------------------------------
__global__ __launch_bounds__(512, 2) void gemm256_qkv(const bf16* __restrict__ A,
                                                      const bf16* __restrict__ B,
                                                      bf16* __restrict__ qb,
                                                      bf16* __restrict__ kb,
                                                      bf16* __restrict__ vt) {
  extern __shared__ char smem[];
  const int t = threadIdx.x;
  const int w = t >> 6, l = t & 63;
  const int lr = l & 15, lg = l >> 4;
  const int wr = w >> 2, wc = w & 3;

  int lin = blockIdx.x;                      // 192 blocks
  lin = (lin & 7) * 24 + (lin >> 3);         // XCD-bijective (192/8=24)
  const int bn = lin % 24, bm = lin / 24;
  const int am0 = bm * 256;                  // A row base
  const int bn0 = bn * 256;                  // B row base (C col base)

  f32x4 acc[8][4] = {};
  bf16x8 a[8];

  // stage one k-half (16KB = 2 loads/thread); dest wave-uniform + lane*16
  auto stageA = [&](int k0, int kh, int buf) {
#pragma unroll
    for (int r = 0; r < 2; ++r) {
      const int c = r * 512 + t;
      const int kc = kh * 4 + (c >> 8);
      const int row = c & 255;
      gload_lds16(A + (size_t)(am0 + row) * 2048 + k0 + kc * 8,
                  smem + buf * 32768 + kh * 16384 + (r * 512 + w * 64) * 16);
    }
  };
  auto stageB = [&](int k0, int kh, int buf) {
#pragma unroll
    for (int r = 0; r < 2; ++r) {
      const int c = r * 512 + t;
      const int kc = kh * 4 + (c >> 8);
      const int row = c & 255;
      gload_lds16(B + (size_t)(bn0 + row) * 2048 + k0 + kc * 8,
                  smem + 65536 + buf * 32768 + kh * 16384 + (r * 512 + w * 64) * 16);
    }
  };

#define LOAD_A(S, buf)                                                        \
  _Pragma("unroll") for (int m = 0; m < 8; ++m) a[m] =                        \
      *(const bf16x8*)(smem + (buf)*32768 + ((S)*4 + lg) * 4096 +             \
                       (wr * 128 + m * 16 + lr) * 16);

#define LOAD_B(S, NH, buf, B0, B1)                                            \
  bf16x8 B0 = *(const bf16x8*)(smem + 65536 + (buf)*32768 +                   \
                               ((S)*4 + lg) * 4096 +                          \
                               (wc * 64 + (NH)*32 + lr) * 16);                \
  bf16x8 B1 = *(const bf16x8*)(smem + 65536 + (buf)*32768 +                   \
                               ((S)*4 + lg) * 4096 +                          \
                               (wc * 64 + (NH)*32 + 16 + lr) * 16);

#define MFMA16(J0, B0, B1)                                                    \
  __builtin_amdgcn_s_setprio(1);                                              \
  _Pragma("unroll") for (int m = 0; m < 8; ++m) {                             \
    acc[m][J0] = __builtin_amdgcn_mfma_f32_16x16x32_bf16(a[m], B0,            \
                                                         acc[m][J0], 0, 0, 0);\
    acc[m][(J0) + 1] = __builtin_amdgcn_mfma_f32_16x16x32_bf16(               \
        a[m], B1, acc[m][(J0) + 1], 0, 0, 0);                                 \
  }                                                                           \
  __builtin_amdgcn_s_setprio(0);

#define BAR __builtin_amdgcn_s_barrier()
#define VMCNT4 asm volatile("s_waitcnt vmcnt(4)" ::: "memory")
#define VMCNT0 asm volatile("s_waitcnt vmcnt(0)" ::: "memory")

  // prologue: tile 0 both k-halves into buf0; vmcnt(4) -> k-half0 landed
  stageA(0, 0, 0);
  stageB(0, 0, 0);
  stageA(0, 1, 0);
  stageB(0, 1, 0);
  VMCNT4;
  BAR;

  for (int tt = 0; tt < 32; ++tt) {
    const int buf = tt & 1;
    const int nbuf = buf ^ 1;
    const int k0n = (tt + 1) * 64;
    const bool pf = (tt < 31);

    // phase 1: k-slab 0, n-half 0
    LOAD_A(0, buf);
    { LOAD_B(0, 0, buf, b0, b1);
      if (pf) stageA(k0n, 0, nbuf);
      BAR;
      MFMA16(0, b0, b1);
      BAR; }
    // phase 2: k-slab 0, n-half 1
    { LOAD_B(0, 1, buf, b0, b1);
      if (pf) stageB(k0n, 0, nbuf);
      BAR;
      MFMA16(2, b0, b1);
      if (pf) { VMCNT4; } else { VMCNT0; }   // guarantees this tile's k-half1
      BAR; }
    // phase 3: k-slab 1, n-half 0
    LOAD_A(1, buf);
    { LOAD_B(1, 0, buf, b0, b1);
      if (pf) stageA(k0n, 1, nbuf);
      BAR;
      MFMA16(0, b0, b1);
      BAR; }
    // phase 4: k-slab 1, n-half 1
    { LOAD_B(1, 1, buf, b0, b1);
      if (pf) stageB(k0n, 1, nbuf);
      BAR;
      MFMA16(2, b0, b1);
      VMCNT4;                                // guarantees next tile's k-half0
      BAR; }
  }

  // epilogue: C/D layout col=lr, row=lg*4+reg
  const int mb = am0 + wr * 128 + lg * 4;
  const int nb = bn0 + wc * 64 + lr;
#pragma unroll
  for (int m = 0; m < 8; ++m) {
    const int mg = mb + m * 16;
#pragma unroll
    for (int j = 0; j < 4; ++j) {
      const int ng = nb + j * 16;
      if (ng < 4096) {
        bf16* dst = (ng < 2048) ? qb : kb;
        const int ngl = ng & 2047;
#pragma unroll
        for (int rr = 0; rr < 4; ++rr)
          dst[(size_t)(mg + rr) * 2048 + ngl] = (bf16)acc[m][j][rr];
      } else {
        bf16x4 pk = {(bf16)acc[m][j][0], (bf16)acc[m][j][1],
                     (bf16)acc[m][j][2], (bf16)acc[m][j][3]};
        *(bf16x4*)(vt + (size_t)(ng - 4096) * 2048 + mg) = pk;
      }
    }
  }
#undef LOAD_A
#undef LOAD_B
#undef MFMA16
#undef BAR
#undef VMCNT4
#undef VMCNT0
}

// ---------------------------------------------------------------------------
// GEMM2 (2048^3): 128^2 m97 structure (256^2 would underfill CUs at M=N=2048).
// ---------------------------------------------------------------------------
__global__ __launch_bounds__(256) void gemm_bt_f32(const bf16* __restrict__ A,
                                                   const bf16* __restrict__ B,
                                                   float* __restrict__ Cf,
                                                   int M, int N, int K) {
  __shared__ bf16 As[128 * 32];
  __shared__ bf16 Bs[128 * 32];
  const int t = threadIdx.x;
  const int w = t >> 6, l = t & 63;
  const int lr = l & 15, lg = l >> 4;
  const int nwg = gridDim.x * gridDim.y;
  int lin = blockIdx.y * gridDim.x + blockIdx.x;
  lin = (lin & 7) * (nwg >> 3) + (lin >> 3);
  const int bn = lin % gridDim.x;
  const int bm = lin / gridDim.x;
  const int wr = w >> 1, wc = w & 1;

  f32x4 acc[4][4] = {};
  const int row0 = t >> 2;
  const int cc0 = (t & 3) * 8;

  for (int k0 = 0; k0 < K; k0 += 32) {
#pragma unroll
    for (int r = 0; r < 2; ++r) {
      const int row = r * 64 + row0;
      gload_lds16(A + (size_t)(bm * 128 + row) * K + k0 + cc0,
                  (char*)As + (r * 256 + w * 64) * 16);
      gload_lds16(B + (size_t)(bn * 128 + row) * K + k0 + cc0,
                  (char*)Bs + (r * 256 + w * 64) * 16);
    }
    __syncthreads();
    bf16x8 af[4], bfr[4];
#pragma unroll
    for (int i = 0; i < 4; ++i) {
      af[i] = *(const bf16x8*)((const char*)As + (wr * 64 + i * 16 + lr) * 64 + lg * 16);
      bfr[i] = *(const bf16x8*)((const char*)Bs + (wc * 64 + i * 16 + lr) * 64 + lg * 16);
    }
#pragma unroll
    for (int mi = 0; mi < 4; ++mi)
#pragma unroll
      for (int ni = 0; ni < 4; ++ni)
        acc[mi][ni] = __builtin_amdgcn_mfma_f32_16x16x32_bf16(af[mi], bfr[ni],
                                                              acc[mi][ni], 0, 0, 0);
    __syncthreads();
  }

  const int mb = bm * 128 + wr * 64 + lg * 4;
  const int nb = bn * 128 + wc * 64 + lr;
#pragma unroll
  for (int mi = 0; mi < 4; ++mi) {
    const int mg = mb + mi * 16;
#pragma unroll
    for (int ni = 0; ni < 4; ++ni) {
      const int ng = nb + ni * 16;
#pragma unroll
      for (int rr = 0; rr < 4; ++rr)
        Cf[(size_t)(mg + rr) * N + ng] = acc[mi][ni][rr];
    }
  }
}

// Flash attention, causal + ALiBi, KVBLK=64, double-buffered, 1 barrier/tile.
__global__ __launch_bounds__(256) void attn_kernel(const bf16* __restrict__ qb,
                                                   const bf16* __restrict__ kb,
                                                   const bf16* __restrict__ vt,
                                                   bf16* __restrict__ out) {
  constexpr int S = 2048, D = 2048;
  __shared__ bf16 Ks[2][64 * 128];
  __shared__ bf16 Vs[2][128 * 64];
  __shared__ bf16 Ps[4][16 * 64];
  const int t = threadIdx.x;
  const int w = t >> 6, l = t & 63;
  const int lr = l & 15, lg = l >> 4;
  const int q0 = (int)(gridDim.x - 1 - blockIdx.x) * 64;
  const int h = blockIdx.y;
  const float slope2 = exp2f(-0.5f * (float)(h + 1)) * 1.4426950408889634f;
  const float scale2 = 0.08838834764831845f * 1.4426950408889634f;

  bf16x8 qf[4];
  {
    const bf16* qrow = qb + (size_t)(q0 + w * 16 + lr) * D + h * 128 + lg * 8;
#pragma unroll
    for (int kk = 0; kk < 4; ++kk) qf[kk] = *(const bf16x8*)(qrow + kk * 32);
  }

  f32x4 ob[8] = {};
  float mrow[4] = {-1e30f, -1e30f, -1e30f, -1e30f};
  float lrow[4] = {0.f, 0.f, 0.f, 0.f};

  const int nt = (q0 >> 6) + 1;

  auto stage = [&](int kv0, int b) {
#pragma unroll
    for (int r = 0; r < 4; ++r) {
      {
        const int krow = r * 16 + (t >> 4);
        const int kcc = t & 15;
        gload_lds16(kb + (size_t)(kv0 + krow) * D + h * 128 + ((kcc ^ (krow & 7)) * 8),
                    (char*)Ks[b] + (r * 256 + w * 64) * 16);
      }
      {
        const int vrow = r * 32 + (t >> 3);
        const int vcc = t & 7;
        gload_lds16(vt + (size_t)(h * 128 + vrow) * S + kv0 + ((vcc ^ (vrow & 7)) * 8),
                    (char*)Vs[b] + (r * 256 + w * 64) * 16);
      }
    }
  };

  stage(0, 0);
  int cur = 0;
  for (int tile = 0; tile < nt; ++tile) {
    __syncthreads();
    if (tile + 1 < nt) stage((tile + 1) << 6, cur ^ 1);
    const int kv0 = tile << 6;

    f32x4 sc[4] = {};
#pragma unroll
    for (int jb = 0; jb < 4; ++jb) {
      const int row = jb * 16 + lr;
#pragma unroll
      for (int kk = 0; kk < 4; ++kk) {
        const int byte = row * 256 + ((kk * 64 + lg * 16) ^ ((row & 7) << 4));
        bf16x8 kf = *(const bf16x8*)((const char*)Ks[cur] + byte);
        sc[jb] = __builtin_amdgcn_mfma_f32_16x16x32_bf16(qf[kk], kf, sc[jb], 0, 0, 0);
      }
    }

    float bias[4];
#pragma unroll
    for (int jb = 0; jb < 4; ++jb)
      bias[jb] = slope2 * (float)(kv0 + jb * 16 + lr - (S - 1));
    const bool diag = (tile == nt - 1);
    float xv[4][4], m2r[4];
#pragma unroll
    for (int rr = 0; rr < 4; ++rr) {
#pragma unroll
      for (int jb = 0; jb < 4; ++jb) {
        float v = fmaf(sc[jb][rr], scale2, bias[jb]);
        if (diag && (jb * 16 + lr > w * 16 + lg * 4 + rr)) v = -1e30f;
        xv[rr][jb] = v;
      }
      float m2 = fmaxf(fmaxf(xv[rr][0], xv[rr][1]), fmaxf(xv[rr][2], xv[rr][3]));
      m2 = fmaxf(m2, __shfl_xor(m2, 1));
      m2 = fmaxf(m2, __shfl_xor(m2, 2));
      m2 = fmaxf(m2, __shfl_xor(m2, 4));
      m2 = fmaxf(m2, __shfl_xor(m2, 8));
      m2r[rr] = m2;
    }
    float need = fmaxf(fmaxf(m2r[0] - mrow[0], m2r[1] - mrow[1]),
                       fmaxf(m2r[2] - mrow[2], m2r[3] - mrow[3]));
    if (!__all(need <= 8.0f)) {
#pragma unroll
      for (int rr = 0; rr < 4; ++rr) {
        const float mnew = fmaxf(mrow[rr], m2r[rr]);
        const float cf = EXP2(mrow[rr] - mnew);
        lrow[rr] *= cf;
        mrow[rr] = mnew;
#pragma unroll
        for (int db = 0; db < 8; ++db) ob[db][rr] *= cf;
      }
    }
    char* pbase = (char*)Ps[w];
#pragma unroll
    for (int rr = 0; rr < 4; ++rr) {
      const int prow = lg * 4 + rr;
      const int sw = (prow & 7) << 4;
      float ps = 0.f;
#pragma unroll
      for (int jb = 0; jb < 4; ++jb) {
        const float p = EXP2(xv[rr][jb] - mrow[rr]);
        *(bf16*)(pbase + ((prow * 128 + jb * 32 + lr * 2) ^ sw)) = (bf16)p;
        ps += p;
      }
      lrow[rr] += ps;
    }

    bf16x8 pf[2];
#pragma unroll
    for (int s = 0; s < 2; ++s)
      pf[s] = *(const bf16x8*)(pbase + ((lr * 128 + s * 64 + lg * 16) ^ ((lr & 7) << 4)));
#pragma unroll
    for (int db = 0; db < 8; ++db) {
      const int vrow = db * 16 + lr;
#pragma unroll
      for (int s = 0; s < 2; ++s) {
        const int byte = vrow * 128 + ((s * 64 + lg * 16) ^ ((vrow & 7) << 4));
        bf16x8 vf = *(const bf16x8*)((const char*)Vs[cur] + byte);
        ob[db] = __builtin_amdgcn_mfma_f32_16x16x32_bf16(pf[s], vf, ob[db], 0, 0, 0);
      }
    }
    cur ^= 1;
  }

#pragma unroll
  for (int rr = 0; rr < 4; ++rr) {
    float ls = lrow[rr];
    ls += __shfl_xor(ls, 1);
    ls += __shfl_xor(ls, 2);
    ls += __shfl_xor(ls, 4);
    ls += __shfl_xor(ls, 8);
    const float inv = 1.0f / ls;
    const int mg = q0 + w * 16 + lg * 4 + rr;
#pragma unroll
    for (int db = 0; db < 8; ++db)
      out[(size_t)mg * D + h * 128 + db * 16 + lr] = (bf16)(ob[db][rr] * inv);
  }
}

extern "C" void kernel_launch(void* const* d_in, const int* in_sizes, int n_in,
                              void* d_out, int out_size, void* d_ws, size_t ws_size,
                              hipStream_t stream) {
  (void)in_sizes; (void)n_in; (void)out_size; (void)ws_size;
  const float* x = (const float*)d_in[0];
  const float* wqkv = (const float*)d_in[1];
  const float* wout = (const float*)d_in[2];
  float* out = (float*)d_out;

  bf16* x_bf = (bf16*)d_ws;
  bf16* wqkv_bf = x_bf + (size_t)2048 * 2048;
  bf16* wout_bf = wqkv_bf + (size_t)6144 * 2048;
  bf16* qb = wout_bf + (size_t)2048 * 2048;
  bf16* kb = qb + (size_t)2048 * 2048;
  bf16* vt = kb + (size_t)2048 * 2048;
  bf16* attn = wqkv_bf;  // wqkv_bf dead after GEMM1

  static int lds_ok = 0;
  if (!lds_ok) {  // idempotent attribute set (not a stream op; capture-safe)
    (void)hipFuncSetAttribute((const void*)gemm256_qkv,
                              hipFuncAttributeMaxDynamicSharedMemorySize, 131072);
    lds_ok = 1;
  }

  cast_f32_bf16<<<4096, 256, 0, stream>>>(x, x_bf, 2048 * 2048);
  cast_f32_bf16<<<12288, 256, 0, stream>>>(wqkv, wqkv_bf, 6144 * 2048);
  cast_f32_bf16<<<4096, 256, 0, stream>>>(wout, wout_bf, 2048 * 2048);

  gemm256_qkv<<<192, 512, 131072, stream>>>(x_bf, wqkv_bf, qb, kb, vt);
  attn_kernel<<<dim3(32, 16), 256, 0, stream>>>(qb, kb, vt, attn);
  gemm_bt_f32<<<dim3(16, 16), 256, 0, stream>>>(attn, wout_bf, out, 2048, 2048, 2048);
}

// Round 6
// 208.217 us; speedup vs baseline: 1.1273x; 1.1273x over previous
//
#include <hip/hip_runtime.h>

typedef __bf16 bf16;
typedef __bf16 bf16x8 __attribute__((ext_vector_type(8)));
typedef __bf16 bf16x4 __attribute__((ext_vector_type(4)));
typedef float f32x4 __attribute__((ext_vector_type(4)));

#if __has_builtin(__builtin_amdgcn_exp2f)
#define EXP2(x) __builtin_amdgcn_exp2f(x)
#else
#define EXP2(x) exp2f(x)
#endif

__device__ __forceinline__ void gload_lds16(const void* g, void* l) {
  __builtin_amdgcn_global_load_lds(
      (const __attribute__((address_space(1))) void*)g,
      (__attribute__((address_space(3))) void*)l, 16, 0, 0);
}

__global__ __launch_bounds__(256) void cast_f32_bf16(const float* __restrict__ in,
                                                     bf16* __restrict__ out, int n) {
  int i = (blockIdx.x * 256 + threadIdx.x) * 4;
  if (i < n) {
    float4 v = *(const float4*)(in + i);
    bf16x4 o = {(bf16)v.x, (bf16)v.y, (bf16)v.z, (bf16)v.w};
    *(bf16x4*)(out + i) = o;
  }
}

// C = A * B^T.  A[M,K], B[N,K] bf16 row-major.  (m97 128^2 structure — known-good)
// EPI 0: float C to Cf. EPI 1: qkv split (q/k natural, v transposed).
template <int EPI>
__global__ __launch_bounds__(256) void gemm_bt(const bf16* __restrict__ A,
                                               const bf16* __restrict__ B,
                                               float* __restrict__ Cf,
                                               bf16* __restrict__ qb,
                                               bf16* __restrict__ kb,
                                               bf16* __restrict__ vt,
                                               int M, int N, int K) {
  __shared__ bf16 As[128 * 32];
  __shared__ bf16 Bs[128 * 32];
  const int t = threadIdx.x;
  const int w = t >> 6, l = t & 63;
  const int lr = l & 15, lg = l >> 4;
  const int nwg = gridDim.x * gridDim.y;
  int lin = blockIdx.y * gridDim.x + blockIdx.x;
  lin = (lin & 7) * (nwg >> 3) + (lin >> 3);  // XCD-bijective (nwg % 8 == 0)
  const int bn = lin % gridDim.x;
  const int bm = lin / gridDim.x;
  const int wr = w >> 1, wc = w & 1;

  f32x4 acc[4][4] = {};
  const int row0 = t >> 2;
  const int cc0 = (t & 3) * 8;

  for (int k0 = 0; k0 < K; k0 += 32) {
#pragma unroll
    for (int r = 0; r < 2; ++r) {
      const int row = r * 64 + row0;
      gload_lds16(A + (size_t)(bm * 128 + row) * K + k0 + cc0,
                  (char*)As + (r * 256 + w * 64) * 16);
      gload_lds16(B + (size_t)(bn * 128 + row) * K + k0 + cc0,
                  (char*)Bs + (r * 256 + w * 64) * 16);
    }
    __syncthreads();
    bf16x8 af[4], bfr[4];
#pragma unroll
    for (int i = 0; i < 4; ++i) {
      af[i] = *(const bf16x8*)((const char*)As + (wr * 64 + i * 16 + lr) * 64 + lg * 16);
      bfr[i] = *(const bf16x8*)((const char*)Bs + (wc * 64 + i * 16 + lr) * 64 + lg * 16);
    }
#pragma unroll
    for (int mi = 0; mi < 4; ++mi)
#pragma unroll
      for (int ni = 0; ni < 4; ++ni)
        acc[mi][ni] = __builtin_amdgcn_mfma_f32_16x16x32_bf16(af[mi], bfr[ni],
                                                              acc[mi][ni], 0, 0, 0);
    __syncthreads();
  }

  const int mb = bm * 128 + wr * 64 + lg * 4;
  const int nb = bn * 128 + wc * 64 + lr;
  if (EPI == 0) {
#pragma unroll
    for (int mi = 0; mi < 4; ++mi) {
      const int mg = mb + mi * 16;
#pragma unroll
      for (int ni = 0; ni < 4; ++ni) {
        const int ng = nb + ni * 16;
#pragma unroll
        for (int rr = 0; rr < 4; ++rr)
          Cf[(size_t)(mg + rr) * N + ng] = acc[mi][ni][rr];
      }
    }
  } else {
    if (bn * 128 < 4096) {
      bf16* dst = (bn * 128 < 2048) ? qb : kb;
#pragma unroll
      for (int mi = 0; mi < 4; ++mi) {
        const int mg = mb + mi * 16;
#pragma unroll
        for (int ni = 0; ni < 4; ++ni) {
          const int ng = (nb + ni * 16) & 2047;
#pragma unroll
          for (int rr = 0; rr < 4; ++rr)
            dst[(size_t)(mg + rr) * 2048 + ng] = (bf16)acc[mi][ni][rr];
        }
      }
    } else {
#pragma unroll
      for (int mi = 0; mi < 4; ++mi) {
        const int mg = mb + mi * 16;
#pragma unroll
        for (int ni = 0; ni < 4; ++ni) {
          const int dc = nb + ni * 16 - 4096;
          bf16x4 pk = {(bf16)acc[mi][ni][0], (bf16)acc[mi][ni][1],
                       (bf16)acc[mi][ni][2], (bf16)acc[mi][ni][3]};
          *(bf16x4*)(vt + (size_t)dc * 2048 + mg) = pk;
        }
      }
    }
  }
}

// Flash attention, causal + ALiBi, KVBLK=64, double-buffered, 1 barrier/tile.
// Grid: 512 blocks flat.  Block b<256 -> heavy q-tile (qt=31-(b>>4)); b>=256 ->
// light complement (qt=(b-256)>>4).  Slots b and b+256 land on the same CU
// under periodic dispatch, so per-CU work sums to a constant 33 tile-units.
__global__ __launch_bounds__(256) void attn_kernel(const bf16* __restrict__ qb,
                                                   const bf16* __restrict__ kb,
                                                   const bf16* __restrict__ vt,
                                                   bf16* __restrict__ out) {
  constexpr int S = 2048, D = 2048;
  __shared__ bf16 Ks[2][64 * 128];
  __shared__ bf16 Vs[2][128 * 64];
  __shared__ bf16 Ps[4][16 * 64];
  const int t = threadIdx.x;
  const int w = t >> 6, l = t & 63;
  const int lr = l & 15, lg = l >> 4;
  const int b = blockIdx.x;
  const int h = b & 15;
  const int qt = (b < 256) ? (31 - (b >> 4)) : ((b - 256) >> 4);
  const int q0 = qt * 64;
  const float slope2 = exp2f(-0.5f * (float)(h + 1)) * 1.4426950408889634f;
  const float scale2 = 0.08838834764831845f * 1.4426950408889634f;

  bf16x8 qf[4];
  {
    const bf16* qrow = qb + (size_t)(q0 + w * 16 + lr) * D + h * 128 + lg * 8;
#pragma unroll
    for (int kk = 0; kk < 4; ++kk) qf[kk] = *(const bf16x8*)(qrow + kk * 32);
  }

  f32x4 ob[8] = {};
  float mrow[4] = {-1e30f, -1e30f, -1e30f, -1e30f};
  float lrow[4] = {0.f, 0.f, 0.f, 0.f};

  const int nt = qt + 1;

  auto stage = [&](int kv0, int bb) {
#pragma unroll
    for (int r = 0; r < 4; ++r) {
      {
        const int krow = r * 16 + (t >> 4);
        const int kcc = t & 15;
        gload_lds16(kb + (size_t)(kv0 + krow) * D + h * 128 + ((kcc ^ (krow & 7)) * 8),
                    (char*)Ks[bb] + (r * 256 + w * 64) * 16);
      }
      {
        const int vrow = r * 32 + (t >> 3);
        const int vcc = t & 7;
        gload_lds16(vt + (size_t)(h * 128 + vrow) * S + kv0 + ((vcc ^ (vrow & 7)) * 8),
                    (char*)Vs[bb] + (r * 256 + w * 64) * 16);
      }
    }
  };

  stage(0, 0);
  int cur = 0;
  for (int tile = 0; tile < nt; ++tile) {
    __syncthreads();
    if (tile + 1 < nt) stage((tile + 1) << 6, cur ^ 1);
    const int kv0 = tile << 6;

    f32x4 sc[4] = {};
#pragma unroll
    for (int jb = 0; jb < 4; ++jb) {
      const int row = jb * 16 + lr;
#pragma unroll
      for (int kk = 0; kk < 4; ++kk) {
        const int byte = row * 256 + ((kk * 64 + lg * 16) ^ ((row & 7) << 4));
        bf16x8 kf = *(const bf16x8*)((const char*)Ks[cur] + byte);
        sc[jb] = __builtin_amdgcn_mfma_f32_16x16x32_bf16(qf[kk], kf, sc[jb], 0, 0, 0);
      }
    }

    float bias[4];
#pragma unroll
    for (int jb = 0; jb < 4; ++jb)
      bias[jb] = slope2 * (float)(kv0 + jb * 16 + lr - (S - 1));
    const bool diag = (tile == nt - 1);
    float xv[4][4], m2r[4];
#pragma unroll
    for (int rr = 0; rr < 4; ++rr) {
#pragma unroll
      for (int jb = 0; jb < 4; ++jb) {
        float v = fmaf(sc[jb][rr], scale2, bias[jb]);
        if (diag && (jb * 16 + lr > w * 16 + lg * 4 + rr)) v = -1e30f;
        xv[rr][jb] = v;
      }
      float m2 = fmaxf(fmaxf(xv[rr][0], xv[rr][1]), fmaxf(xv[rr][2], xv[rr][3]));
      m2 = fmaxf(m2, __shfl_xor(m2, 1));
      m2 = fmaxf(m2, __shfl_xor(m2, 2));
      m2 = fmaxf(m2, __shfl_xor(m2, 4));
      m2 = fmaxf(m2, __shfl_xor(m2, 8));
      m2r[rr] = m2;
    }
    float need = fmaxf(fmaxf(m2r[0] - mrow[0], m2r[1] - mrow[1]),
                       fmaxf(m2r[2] - mrow[2], m2r[3] - mrow[3]));
    if (!__all(need <= 8.0f)) {
#pragma unroll
      for (int rr = 0; rr < 4; ++rr) {
        const float mnew = fmaxf(mrow[rr], m2r[rr]);
        const float cf = EXP2(mrow[rr] - mnew);
        lrow[rr] *= cf;
        mrow[rr] = mnew;
#pragma unroll
        for (int db = 0; db < 8; ++db) ob[db][rr] *= cf;
      }
    }
    char* pbase = (char*)Ps[w];
#pragma unroll
    for (int rr = 0; rr < 4; ++rr) {
      const int prow = lg * 4 + rr;
      const int sw = (prow & 7) << 4;
      float ps = 0.f;
#pragma unroll
      for (int jb = 0; jb < 4; ++jb) {
        const float p = EXP2(xv[rr][jb] - mrow[rr]);
        *(bf16*)(pbase + ((prow * 128 + jb * 32 + lr * 2) ^ sw)) = (bf16)p;
        ps += p;
      }
      lrow[rr] += ps;
    }

    bf16x8 pf[2];
#pragma unroll
    for (int s = 0; s < 2; ++s)
      pf[s] = *(const bf16x8*)(pbase + ((lr * 128 + s * 64 + lg * 16) ^ ((lr & 7) << 4)));
#pragma unroll
    for (int db = 0; db < 8; ++db) {
      const int vrow = db * 16 + lr;
#pragma unroll
      for (int s = 0; s < 2; ++s) {
        const int byte = vrow * 128 + ((s * 64 + lg * 16) ^ ((vrow & 7) << 4));
        bf16x8 vf = *(const bf16x8*)((const char*)Vs[cur] + byte);
        ob[db] = __builtin_amdgcn_mfma_f32_16x16x32_bf16(pf[s], vf, ob[db], 0, 0, 0);
      }
    }
    cur ^= 1;
  }

#pragma unroll
  for (int rr = 0; rr < 4; ++rr) {
    float ls = lrow[rr];
    ls += __shfl_xor(ls, 1);
    ls += __shfl_xor(ls, 2);
    ls += __shfl_xor(ls, 4);
    ls += __shfl_xor(ls, 8);
    const float inv = 1.0f / ls;
    const int mg = q0 + w * 16 + lg * 4 + rr;
#pragma unroll
    for (int db = 0; db < 8; ++db)
      out[(size_t)mg * D + h * 128 + db * 16 + lr] = (bf16)(ob[db][rr] * inv);
  }
}

extern "C" void kernel_launch(void* const* d_in, const int* in_sizes, int n_in,
                              void* d_out, int out_size, void* d_ws, size_t ws_size,
                              hipStream_t stream) {
  (void)in_sizes; (void)n_in; (void)out_size; (void)ws_size;
  const float* x = (const float*)d_in[0];
  const float* wqkv = (const float*)d_in[1];
  const float* wout = (const float*)d_in[2];
  float* out = (float*)d_out;

  bf16* x_bf = (bf16*)d_ws;
  bf16* wqkv_bf = x_bf + (size_t)2048 * 2048;
  bf16* wout_bf = wqkv_bf + (size_t)6144 * 2048;
  bf16* qb = wout_bf + (size_t)2048 * 2048;
  bf16* kb = qb + (size_t)2048 * 2048;
  bf16* vt = kb + (size_t)2048 * 2048;
  bf16* attn = wqkv_bf;  // wqkv_bf dead after GEMM1

  cast_f32_bf16<<<4096, 256, 0, stream>>>(x, x_bf, 2048 * 2048);
  cast_f32_bf16<<<12288, 256, 0, stream>>>(wqkv, wqkv_bf, 6144 * 2048);
  cast_f32_bf16<<<4096, 256, 0, stream>>>(wout, wout_bf, 2048 * 2048);

  gemm_bt<1><<<dim3(48, 16), 256, 0, stream>>>(x_bf, wqkv_bf, nullptr, qb, kb, vt,
                                               2048, 6144, 2048);
  attn_kernel<<<512, 256, 0, stream>>>(qb, kb, vt, attn);
  gemm_bt<0><<<dim3(16, 16), 256, 0, stream>>>(attn, wout_bf, out, nullptr, nullptr,
                                               nullptr, 2048, 2048, 2048);
}